// Round 3
// baseline (260.701 us; speedup 1.0000x reference)
//
#include <hip/hip_runtime.h>
#include <hip/hip_fp16.h>

#define PI_F 3.14159265358979323846f
#define INV_SQRT2 0.70710678118654752440f

__device__ __forceinline__ float2 cmul(float2 a, float2 b) {
    return make_float2(a.x*b.x - a.y*b.y, a.x*b.y + a.y*b.x);
}

// RY on a register-bit qubit (j-bit BIT). float2 packs re/im -> v_pk_fma_f32.
template<int BIT>
__device__ __forceinline__ void reg_gate(float2* a, float c, float s) {
#pragma unroll
    for (int j = 0; j < 32; ++j) {
        if (!(j & BIT)) {
            const int k = j | BIT;
            const float2 a0 = a[j], a1 = a[k];
            a[j] = make_float2(c*a0.x - s*a1.x, c*a0.y - s*a1.y);
            a[k] = make_float2(s*a0.x + c*a1.x, s*a0.y + c*a1.y);
        }
    }
}

// RY on a lane-bit qubit: cross-lane shuffle (no LDS, no sync).
__device__ __forceinline__ void lane_gate(float2* a, int l, int mask, float c, float s) {
    const float sg = (l & mask) ? s : -s;
#pragma unroll
    for (int j = 0; j < 32; ++j) {
        const float px = __shfl_xor(a[j].x, mask, 64);
        const float py = __shfl_xor(a[j].y, mask, 64);
        a[j] = make_float2(c*a[j].x + sg*px, c*a[j].y + sg*py);
    }
}

// 8-block group barrier. Device-scope release/acquire atomics (cross-XCD safe,
// G16). Counters pre-zeroed by hipMemsetAsync. Each counter used exactly once.
__device__ __forceinline__ void group_barrier(unsigned* cnt, int tid) {
    __syncthreads();                       // all waves' stores drained (vmcnt 0)
    if (tid == 0) {
        __threadfence();                   // belt: flush to device scope
        __hip_atomic_fetch_add(cnt, 1u, __ATOMIC_RELEASE, __HIP_MEMORY_SCOPE_AGENT);
        while (__hip_atomic_load(cnt, __ATOMIC_ACQUIRE, __HIP_MEMORY_SCOPE_AGENT) < 8u)
            __builtin_amdgcn_s_sleep(2);
        __threadfence();                   // invalidate caches before readers run
    }
    __syncthreads();
}

// One fused kernel: 512 blocks, group = 8 blocks per circuit.
// XCD swizzle keeps a group's blocks together (perf only, not correctness).
__global__ __launch_bounds__(256, 2)
void fused_qsim(const float* __restrict__ x, const float* __restrict__ wcrz,
                const float* __restrict__ wry, const float* __restrict__ scale_p,
                __half2* __restrict__ st, unsigned* __restrict__ bar,
                float* __restrict__ accum, float* __restrict__ out) {
    const int tid = threadIdx.x;
    const int xs = blockIdx.x & 7, kk = blockIdx.x >> 3;
    const int n = (xs << 3) | (kk >> 3);   // circuit 0..63
    const int g = kk & 7;                  // chunk block 0..7
    const int l = tid & 63, wid = tid >> 6;

    __shared__ float v0s[16], v1s[16], t0s[16], gc[16], gs[16];
    __shared__ float2 TL[256], TH[256], C0[16];
    __shared__ float t1s[16], bc[16], bs[16], ac5[5], as5[5];
    __shared__ float2 A1[256], B1[128], D1[128];
    __shared__ float wz[4][16];

    float2 a[32];

    // ================= Phase A: init product state * phi0, RY(alpha) bits 0..10
    // Amp index: bits0-5 = lane, bits6-10 = j, bits11-15 = w (chunk).
    {
        const int w = g * 4 + wid;
        if (tid < 16) {
            const int q = tid, b = n >> 3, p = n & 7, h = q >> 2, ww = q & 3;
            const float enc = tanhf(x[b*128 + h*32 + p*4 + ww] * scale_p[0]) * PI_F;
            float sE, cE; sincosf(0.5f * enc, &sE, &cE);
            v0s[q] = (cE - sE) * INV_SQRT2;     // RY(enc)*H |0>
            v1s[q] = (cE + sE) * INV_SQRT2;
            sincosf(0.5f * (wry[q] + enc), &gs[q], &gc[q]);  // merged RY(w0+enc)
            t0s[q] = 0.5f * wcrz[q];            // layer-0 CRZ half-angles
        }
        __syncthreads();

        {   // TL: state bits 0..7 (product + crz q=0..6); TH: bits 8..15 (q=8..14)
            float prod = 1.f, ang = 0.f;
#pragma unroll
            for (int q = 0; q < 8; ++q) prod *= ((tid >> q) & 1) ? v1s[q] : v0s[q];
#pragma unroll
            for (int i = 0; i < 7; ++i)
                if ((tid >> i) & 1) ang += ((tid >> (i + 1)) & 1) ? t0s[i] : -t0s[i];
            float sa, ca; sincosf(ang, &sa, &ca);
            TL[tid] = make_float2(prod * ca, prod * sa);

            prod = 1.f; ang = 0.f;
#pragma unroll
            for (int q = 0; q < 8; ++q) prod *= ((tid >> q) & 1) ? v1s[q + 8] : v0s[q + 8];
#pragma unroll
            for (int i = 0; i < 7; ++i)
                if ((tid >> i) & 1) ang += ((tid >> (i + 1)) & 1) ? t0s[8 + i] : -t0s[8 + i];
            sincosf(ang, &sa, &ca);
            TH[tid] = make_float2(prod * ca, prod * sa);

            if (tid < 16) {  // cross gates q=7 (b7->b8), q=15 (b15->b0)
                const int b7 = tid & 1, b8 = (tid >> 1) & 1, b15 = (tid >> 2) & 1, b0 = (tid >> 3) & 1;
                float a2 = 0.f;
                if (b7)  a2 += b8 ? t0s[7]  : -t0s[7];
                if (b15) a2 += b0 ? t0s[15] : -t0s[15];
                float s2, c2; sincosf(a2, &s2, &c2);
                C0[tid] = make_float2(c2, s2);
            }
        }
        __syncthreads();

        {
            const int b0 = l & 1, b15 = (w >> 4) & 1;
            float2 G[8];
#pragma unroll
            for (int u = 0; u < 8; ++u) {       // u = j&7 -> state bits 6,7,8
                const int b7 = (u >> 1) & 1, b8 = (u >> 2) & 1;
                G[u] = cmul(TL[l | ((u & 3) << 6)],
                            C0[b7 | (b8 << 1) | (b15 << 2) | (b0 << 3)]);
            }
#pragma unroll
            for (int j = 0; j < 32; ++j)
                a[j] = cmul(G[j & 7], TH[((j >> 2) & 7) | (w << 3)]);
        }

        reg_gate<1 >(a, gc[6],  gs[6]);
        reg_gate<2 >(a, gc[7],  gs[7]);
        reg_gate<4 >(a, gc[8],  gs[8]);
        reg_gate<8 >(a, gc[9],  gs[9]);
        reg_gate<16>(a, gc[10], gs[10]);
#pragma unroll
        for (int q = 0; q < 6; ++q) lane_gate(a, l, 1 << q, gc[q], gs[q]);

        __half2* op = st + ((size_t)n << 16) + (w << 11) + l;
#pragma unroll
        for (int j = 0; j < 32; ++j) op[j << 6] = __floats2half2_rn(a[j].x, a[j].y);
    }

    group_barrier(&bar[n * 3 + 0], tid);

    // ================= Phase B: RY(alpha) bits 11..15, phi1, RY(beta) bits 0..5,11..15
    // Amp index: bits0-5 = lane, bits6-10 = v (chunk), bits11-15 = j.
    {
        const int v = g * 4 + wid;
        if (tid < 16) {
            const int q = tid, b = n >> 3, p = n & 7, h = q >> 2, ww = q & 3;
            const float enc = tanhf(x[b*128 + h*32 + p*4 + ww] * scale_p[0]) * PI_F;
            if (q >= 11) sincosf(0.5f * (wry[q] + enc), &as5[q - 11], &ac5[q - 11]);
            sincosf(0.5f * wry[16 + q], &bs[q], &bc[q]);
            t1s[q] = 0.5f * wcrz[16 + q];
        }
        __syncthreads();

        {   // A1: idx bits0-5 = state 0..5, bits6,7 = state 6,7 (gates q=0..5)
            float ang = 0.f;
#pragma unroll
            for (int i = 0; i < 6; ++i)
                if ((tid >> i) & 1) ang += ((tid >> (i + 2)) & 1) ? t1s[i] : -t1s[i];
            float s, c; sincosf(ang, &s, &c);
            A1[tid] = make_float2(c, s);

            if (tid < 128) {  // B1: idx bits0-4 = state 6..10, bits5,6 = state 11,12 (q=6..10)
                const int t = tid;
                ang = 0.f;
#pragma unroll
                for (int i = 0; i < 5; ++i)
                    if ((t >> i) & 1) ang += ((t >> (i + 2)) & 1) ? t1s[6 + i] : -t1s[6 + i];
                sincosf(ang, &s, &c);
                B1[t] = make_float2(c, s);
            } else {          // D1: idx bits0-4 = state 11..15, bits5,6 = state 0,1 (q=11..15)
                const int t = tid - 128;
                ang = 0.f;
#pragma unroll
                for (int i = 0; i < 5; ++i)
                    if ((t >> i) & 1) ang += ((t >> (i + 2)) & 1) ? t1s[11 + i] : -t1s[11 + i];
                sincosf(ang, &s, &c);
                D1[t] = make_float2(c, s);
            }
        }
        __syncthreads();

        __half2* base = st + ((size_t)n << 16) + (v << 6) + l;
#pragma unroll
        for (int j = 0; j < 32; ++j) a[j] = __half22float2(base[j << 11]);

        reg_gate<1 >(a, ac5[0], as5[0]);
        reg_gate<2 >(a, ac5[1], as5[1]);
        reg_gate<4 >(a, ac5[2], as5[2]);
        reg_gate<8 >(a, ac5[3], as5[3]);
        reg_gate<16>(a, ac5[4], as5[4]);

        {   // phi1 pointwise: phase = A1 * B1 * D1
            const float2 pa = A1[l | ((v & 3) << 6)];
            float2 PB[4];
#pragma unroll
            for (int t = 0; t < 4; ++t) PB[t] = cmul(pa, B1[v | (t << 5)]);
            const int dl = (l & 3) << 5;
#pragma unroll
            for (int j = 0; j < 32; ++j)
                a[j] = cmul(a[j], cmul(PB[j & 3], D1[j | dl]));
        }

#pragma unroll
        for (int q = 0; q < 6; ++q) lane_gate(a, l, 1 << q, bc[q], bs[q]);
        reg_gate<1 >(a, bc[11], bs[11]);
        reg_gate<2 >(a, bc[12], bs[12]);
        reg_gate<4 >(a, bc[13], bs[13]);
        reg_gate<8 >(a, bc[14], bs[14]);
        reg_gate<16>(a, bc[15], bs[15]);

#pragma unroll
        for (int j = 0; j < 32; ++j) base[j << 11] = __floats2half2_rn(a[j].x, a[j].y);
    }

    group_barrier(&bar[n * 3 + 1], tid);

    // ================= Phase C: RY(beta) bits 6..10 + measure
    {
        const int w = g * 4 + wid;
        float c5[5], s5[5];
#pragma unroll
        for (int i = 0; i < 5; ++i) sincosf(0.5f * wry[16 + 6 + i], &s5[i], &c5[i]);

        const __half2* base = st + ((size_t)n << 16) + (w << 11) + l;
#pragma unroll
        for (int j = 0; j < 32; ++j) a[j] = __half22float2(base[j << 6]);

        reg_gate<1 >(a, c5[0], s5[0]);
        reg_gate<2 >(a, c5[1], s5[1]);
        reg_gate<4 >(a, c5[2], s5[2]);
        reg_gate<8 >(a, c5[3], s5[3]);
        reg_gate<16>(a, c5[4], s5[4]);

        float vals[12];
#pragma unroll
        for (int i = 0; i < 12; ++i) vals[i] = 0.f;
#pragma unroll
        for (int j = 0; j < 32; ++j) {
            const float p = a[j].x*a[j].x + a[j].y*a[j].y;
            vals[0] += p;
#pragma unroll
            for (int i = 0; i < 5; ++i) if ((j >> i) & 1) vals[1 + i] += p;
        }
#pragma unroll
        for (int i = 0; i < 6; ++i) vals[6 + i] = ((l >> i) & 1) ? vals[0] : 0.f;

#pragma unroll
        for (int off = 1; off < 64; off <<= 1)
#pragma unroll
            for (int i = 0; i < 12; ++i) vals[i] += __shfl_xor(vals[i], off, 64);

        if (l == 0) {
            const float P = vals[0];
            float z[16];
#pragma unroll
            for (int i = 0; i < 6; ++i) z[i] = P - 2.f * vals[6 + i];       // lane bits
#pragma unroll
            for (int i = 0; i < 5; ++i) z[6 + i] = P - 2.f * vals[1 + i];   // j bits
#pragma unroll
            for (int i = 0; i < 5; ++i) z[11 + i] = ((w >> i) & 1) ? -P : P; // chunk bits
#pragma unroll
            for (int q = 0; q < 16; ++q) wz[wid][q] = z[q];
        }
        __syncthreads();
        if (tid < 16)
            atomicAdd(&accum[n * 16 + tid],
                      wz[0][tid] + wz[1][tid] + wz[2][tid] + wz[3][tid]);
    }

    group_barrier(&bar[n * 3 + 2], tid);

    // ================= Finalize: g==0 block writes circuit n's 16 outputs
    if (g == 0 && tid < 16) {
        const int q = tid, b = n >> 3, p = n & 7, h = q >> 2, ww = q & 3;
        const float s = accum[n * 16 + q];
        out[b*128 + h*32 + p*4 + ww] = fminf(1.f, fmaxf(-1.f, s));
    }
}

extern "C" void kernel_launch(void* const* d_in, const int* in_sizes, int n_in,
                              void* d_out, int out_size, void* d_ws, size_t ws_size,
                              hipStream_t stream) {
    const float* x     = (const float*)d_in[0];
    const float* wcrz  = (const float*)d_in[1];
    const float* wry   = (const float*)d_in[2];
    const float* scale = (const float*)d_in[3];

    __half2* st = (__half2*)d_ws;                                // 64*65536*4 B = 16 MB
    char* ctrl = (char*)d_ws + (size_t)64 * 65536 * sizeof(__half2);
    unsigned* bar = (unsigned*)ctrl;                             // 64*3 counters
    float* accum  = (float*)(ctrl + 64 * 3 * sizeof(unsigned));  // 64*16 floats
    const size_t ctrl_bytes = 64 * 3 * sizeof(unsigned) + 64 * 16 * sizeof(float);
    float* out = (float*)d_out;

    hipMemsetAsync(ctrl, 0, ctrl_bytes, stream);
    fused_qsim<<<512, 256, 0, stream>>>(x, wcrz, wry, scale, st, bar, accum, out);
}

// Round 4
// 147.255 us; speedup vs baseline: 1.7704x; 1.7704x over previous
//
#include <hip/hip_runtime.h>
#include <hip/hip_fp16.h>

#define PI_F 3.14159265358979323846f
#define INV_SQRT2 0.70710678118654752440f

__device__ __forceinline__ float2 cmul(float2 a, float2 b) {
    return make_float2(a.x*b.x - a.y*b.y, a.x*b.y + a.y*b.x);
}

// RY on a register-bit qubit (j-bit BIT). float2 packs re/im -> v_pk_fma_f32.
template<int BIT>
__device__ __forceinline__ void reg_gate(float2* a, float c, float s) {
#pragma unroll
    for (int j = 0; j < 32; ++j) {
        if (!(j & BIT)) {
            const int k = j | BIT;
            const float2 a0 = a[j], a1 = a[k];
            a[j] = make_float2(c*a0.x - s*a1.x, c*a0.y - s*a1.y);
            a[k] = make_float2(s*a0.x + c*a1.x, s*a0.y + c*a1.y);
        }
    }
}

// RY on a lane-bit qubit: cross-lane shuffle (no LDS, no sync).
__device__ __forceinline__ void lane_gate(float2* a, int l, int mask, float c, float s) {
    const float sg = (l & mask) ? s : -s;
#pragma unroll
    for (int j = 0; j < 32; ++j) {
        const float px = __shfl_xor(a[j].x, mask, 64);
        const float py = __shfl_xor(a[j].y, mask, 64);
        a[j] = make_float2(c*a[j].x + sg*px, c*a[j].y + sg*py);
    }
}

// Block decode with XCD swizzle: all 8 blocks of a circuit share blockIdx%8,
// so one circuit's 256 KB fp16 state stays in a single XCD's 4 MB L2
// (8 circuits/XCD * 256 KB = 2 MB).
#define DECODE_BLOCK() \
    const int tid = threadIdx.x; \
    const int xs = blockIdx.x & 7, kk = blockIdx.x >> 3; \
    const int n = (xs << 3) | (kk >> 3); \
    const int g = kk & 7; \
    const int l = tid & 63, wid = tid >> 6;

// ---------------- K1: init product state * phi0, RY(alpha) on state bits 0..10.
// Amp index: bits0-5 = lane, bits6-10 = j, bits11-15 = w (chunk).
__global__ __launch_bounds__(256, 2)
void k1_init(const float* __restrict__ x, const float* __restrict__ wcrz,
             const float* __restrict__ wry, const float* __restrict__ scale_p,
             __half2* __restrict__ st) {
    DECODE_BLOCK();
    const int w = g * 4 + wid;   // chunk bits 11..15

    __shared__ float v0s[16], v1s[16], t0s[16], gc[16], gs[16];
    __shared__ float2 TL[256], TH[256], C0[16];

    if (tid < 16) {
        const int q = tid, b = n >> 3, p = n & 7, h = q >> 2, ww = q & 3;
        const float enc = tanhf(x[b*128 + h*32 + p*4 + ww] * scale_p[0]) * PI_F;
        float sE, cE; sincosf(0.5f * enc, &sE, &cE);
        v0s[q] = (cE - sE) * INV_SQRT2;      // RY(enc)*H |0>
        v1s[q] = (cE + sE) * INV_SQRT2;
        sincosf(0.5f * (wry[q] + enc), &gs[q], &gc[q]);  // merged RY(w0)+RY(enc)
        t0s[q] = 0.5f * wcrz[q];             // layer-0 CRZ half-angles
    }
    __syncthreads();

    {   // TL: state bits 0..7 (product + crz gates q=0..6)
        float prod = 1.f, ang = 0.f;
#pragma unroll
        for (int q = 0; q < 8; ++q) prod *= ((tid >> q) & 1) ? v1s[q] : v0s[q];
#pragma unroll
        for (int i = 0; i < 7; ++i)
            if ((tid >> i) & 1) ang += ((tid >> (i + 1)) & 1) ? t0s[i] : -t0s[i];
        float sa, ca; sincosf(ang, &sa, &ca);
        TL[tid] = make_float2(prod * ca, prod * sa);

        // TH: state bits 8..15 (product + crz gates q=8..14)
        prod = 1.f; ang = 0.f;
#pragma unroll
        for (int q = 0; q < 8; ++q) prod *= ((tid >> q) & 1) ? v1s[q + 8] : v0s[q + 8];
#pragma unroll
        for (int i = 0; i < 7; ++i)
            if ((tid >> i) & 1) ang += ((tid >> (i + 1)) & 1) ? t0s[8 + i] : -t0s[8 + i];
        sincosf(ang, &sa, &ca);
        TH[tid] = make_float2(prod * ca, prod * sa);

        if (tid < 16) {  // cross gates q=7 (b7->b8), q=15 (b15->b0)
            const int b7 = tid & 1, b8 = (tid >> 1) & 1, b15 = (tid >> 2) & 1, b0 = (tid >> 3) & 1;
            float a2 = 0.f;
            if (b7)  a2 += b8 ? t0s[7]  : -t0s[7];
            if (b15) a2 += b0 ? t0s[15] : -t0s[15];
            float s2, c2; sincosf(a2, &s2, &c2);
            C0[tid] = make_float2(c2, s2);
        }
    }
    __syncthreads();

    float2 a[32];
    {
        const int b0 = l & 1, b15 = (w >> 4) & 1;
        float2 G[8];
#pragma unroll
        for (int u = 0; u < 8; ++u) {           // u = j&7 -> state bits 6,7,8
            const int b7 = (u >> 1) & 1, b8 = (u >> 2) & 1;
            G[u] = cmul(TL[l | ((u & 3) << 6)],
                        C0[b7 | (b8 << 1) | (b15 << 2) | (b0 << 3)]);
        }
#pragma unroll
        for (int j = 0; j < 32; ++j)
            a[j] = cmul(G[j & 7], TH[((j >> 2) & 7) | (w << 3)]);
    }

    // RY(alpha) on state bits 6..10 (j bits) and 0..5 (lane bits)
    reg_gate<1 >(a, gc[6],  gs[6]);
    reg_gate<2 >(a, gc[7],  gs[7]);
    reg_gate<4 >(a, gc[8],  gs[8]);
    reg_gate<8 >(a, gc[9],  gs[9]);
    reg_gate<16>(a, gc[10], gs[10]);
#pragma unroll
    for (int q = 0; q < 6; ++q) lane_gate(a, l, 1 << q, gc[q], gs[q]);

    __half2* op = st + ((size_t)n << 16) + (w << 11) + l;
#pragma unroll
    for (int j = 0; j < 32; ++j) op[j << 6] = __floats2half2_rn(a[j].x, a[j].y);
}

// ---------------- K2: RY(alpha) bits 11..15, phi1, RY(beta) bits 0..5,11..15.
// Amp index: bits0-5 = lane, bits6-10 = v (chunk), bits11-15 = j.
__global__ __launch_bounds__(256, 2)
void k2_mid(const float* __restrict__ x, const float* __restrict__ wcrz,
            const float* __restrict__ wry, const float* __restrict__ scale_p,
            __half2* __restrict__ st) {
    DECODE_BLOCK();
    const int v = g * 4 + wid;   // chunk bits 6..10

    __shared__ float t1s[16], bc[16], bs[16], ac5[5], as5[5];
    __shared__ float2 A1[256], B1[128], D1[128];

    if (tid < 16) {
        const int q = tid, b = n >> 3, p = n & 7, h = q >> 2, ww = q & 3;
        const float enc = tanhf(x[b*128 + h*32 + p*4 + ww] * scale_p[0]) * PI_F;
        if (q >= 11) sincosf(0.5f * (wry[q] + enc), &as5[q - 11], &ac5[q - 11]);
        sincosf(0.5f * wry[16 + q], &bs[q], &bc[q]);
        t1s[q] = 0.5f * wcrz[16 + q];
    }
    __syncthreads();

    {   // A1: idx bits 0..5 = state 0..5, bits 6,7 = state 6,7. gates q=0..5
        float ang = 0.f;
#pragma unroll
        for (int i = 0; i < 6; ++i)
            if ((tid >> i) & 1) ang += ((tid >> (i + 2)) & 1) ? t1s[i] : -t1s[i];
        float s, c; sincosf(ang, &s, &c);
        A1[tid] = make_float2(c, s);

        if (tid < 128) {  // B1: idx bits 0..4 = state 6..10, bits 5,6 = state 11,12. gates q=6..10
            const int t = tid;
            ang = 0.f;
#pragma unroll
            for (int i = 0; i < 5; ++i)
                if ((t >> i) & 1) ang += ((t >> (i + 2)) & 1) ? t1s[6 + i] : -t1s[6 + i];
            sincosf(ang, &s, &c);
            B1[t] = make_float2(c, s);
        } else {          // D1: idx bits 0..4 = state 11..15, bits 5,6 = state 0,1. gates q=11..15
            const int t = tid - 128;
            ang = 0.f;
#pragma unroll
            for (int i = 0; i < 5; ++i)
                if ((t >> i) & 1) ang += ((t >> (i + 2)) & 1) ? t1s[11 + i] : -t1s[11 + i];
            sincosf(ang, &s, &c);
            D1[t] = make_float2(c, s);
        }
    }
    __syncthreads();

    float2 a[32];
    __half2* base = st + ((size_t)n << 16) + (v << 6) + l;
#pragma unroll
    for (int j = 0; j < 32; ++j) a[j] = __half22float2(base[j << 11]);

    // finish RY(alpha): state bits 11..15 = j bits
    reg_gate<1 >(a, ac5[0], as5[0]);
    reg_gate<2 >(a, ac5[1], as5[1]);
    reg_gate<4 >(a, ac5[2], as5[2]);
    reg_gate<8 >(a, ac5[3], as5[3]);
    reg_gate<16>(a, ac5[4], as5[4]);

    // phi1 pointwise: phase = A1 * B1 * D1
    {
        const float2 pa = A1[l | ((v & 3) << 6)];
        float2 PB[4];
#pragma unroll
        for (int t = 0; t < 4; ++t) PB[t] = cmul(pa, B1[v | (t << 5)]);
        const int dl = (l & 3) << 5;
#pragma unroll
        for (int j = 0; j < 32; ++j)
            a[j] = cmul(a[j], cmul(PB[j & 3], D1[j | dl]));
    }

    // RY(beta) on lane bits 0..5 and j bits 11..15
#pragma unroll
    for (int q = 0; q < 6; ++q) lane_gate(a, l, 1 << q, bc[q], bs[q]);
    reg_gate<1 >(a, bc[11], bs[11]);
    reg_gate<2 >(a, bc[12], bs[12]);
    reg_gate<4 >(a, bc[13], bs[13]);
    reg_gate<8 >(a, bc[14], bs[14]);
    reg_gate<16>(a, bc[15], bs[15]);

#pragma unroll
    for (int j = 0; j < 32; ++j) base[j << 11] = __floats2half2_rn(a[j].x, a[j].y);
}

// ---------------- K3: RY(beta) bits 6..10 + measure + last-block finalize.
__global__ __launch_bounds__(256, 2)
void k3_measure(const float* __restrict__ wry, const __half2* __restrict__ st,
                float* __restrict__ accum, unsigned* __restrict__ done,
                float* __restrict__ out) {
    DECODE_BLOCK();
    const int w = g * 4 + wid;   // chunk bits 11..15

    float c5[5], s5[5];
#pragma unroll
    for (int i = 0; i < 5; ++i) sincosf(0.5f * wry[16 + 6 + i], &s5[i], &c5[i]);

    float2 a[32];
    const __half2* base = st + ((size_t)n << 16) + (w << 11) + l;
#pragma unroll
    for (int j = 0; j < 32; ++j) a[j] = __half22float2(base[j << 6]);

    reg_gate<1 >(a, c5[0], s5[0]);
    reg_gate<2 >(a, c5[1], s5[1]);
    reg_gate<4 >(a, c5[2], s5[2]);
    reg_gate<8 >(a, c5[3], s5[3]);
    reg_gate<16>(a, c5[4], s5[4]);

    // vals: P, T0..T4 (j-bit masked sums), M0..M5 (lane-bit masked = P or 0)
    float vals[12];
#pragma unroll
    for (int i = 0; i < 12; ++i) vals[i] = 0.f;
#pragma unroll
    for (int j = 0; j < 32; ++j) {
        const float p = a[j].x*a[j].x + a[j].y*a[j].y;
        vals[0] += p;
#pragma unroll
        for (int i = 0; i < 5; ++i) if ((j >> i) & 1) vals[1 + i] += p;
    }
#pragma unroll
    for (int i = 0; i < 6; ++i) vals[6 + i] = ((l >> i) & 1) ? vals[0] : 0.f;

#pragma unroll
    for (int off = 1; off < 64; off <<= 1)
#pragma unroll
        for (int i = 0; i < 12; ++i) vals[i] += __shfl_xor(vals[i], off, 64);

    __shared__ float wz[4][16];
    __shared__ int lastflag;
    if (l == 0) {
        const float P = vals[0];
        float z[16];
#pragma unroll
        for (int i = 0; i < 6; ++i) z[i] = P - 2.f * vals[6 + i];        // lane bits
#pragma unroll
        for (int i = 0; i < 5; ++i) z[6 + i] = P - 2.f * vals[1 + i];    // j bits 6..10
#pragma unroll
        for (int i = 0; i < 5; ++i) z[11 + i] = ((w >> i) & 1) ? -P : P; // chunk bits
#pragma unroll
        for (int q = 0; q < 16; ++q) wz[wid][q] = z[q];
    }
    __syncthreads();
    if (tid < 16)
        atomicAdd(&accum[n * 16 + tid],
                  wz[0][tid] + wz[1][tid] + wz[2][tid] + wz[3][tid]);
    __threadfence();           // make this block's adds visible device-wide
    __syncthreads();
    if (tid == 0) {
        const unsigned t = __hip_atomic_fetch_add(&done[n], 1u, __ATOMIC_ACQ_REL,
                                                  __HIP_MEMORY_SCOPE_AGENT);
        lastflag = (t == 7u);  // last arriver sees all 8 blocks' adds
    }
    __syncthreads();
    if (lastflag && tid < 16) {
        const int q = tid, b = n >> 3, p = n & 7, h = q >> 2, ww = q & 3;
        const float s = accum[n * 16 + q];
        out[b*128 + h*32 + p*4 + ww] = fminf(1.f, fmaxf(-1.f, s));
    }
}

extern "C" void kernel_launch(void* const* d_in, const int* in_sizes, int n_in,
                              void* d_out, int out_size, void* d_ws, size_t ws_size,
                              hipStream_t stream) {
    const float* x     = (const float*)d_in[0];
    const float* wcrz  = (const float*)d_in[1];
    const float* wry   = (const float*)d_in[2];
    const float* scale = (const float*)d_in[3];

    __half2* st = (__half2*)d_ws;                                // 64*65536*4 B = 16 MB
    char* ctrl  = (char*)d_ws + (size_t)64 * 65536 * sizeof(__half2);
    float* accum   = (float*)ctrl;                               // 64*16 floats
    unsigned* done = (unsigned*)(ctrl + 64 * 16 * sizeof(float)); // 64 counters
    const size_t ctrl_bytes = 64 * 16 * sizeof(float) + 64 * sizeof(unsigned);
    float* out = (float*)d_out;

    hipMemsetAsync(ctrl, 0, ctrl_bytes, stream);
    k1_init   <<<512, 256, 0, stream>>>(x, wcrz, wry, scale, st);
    k2_mid    <<<512, 256, 0, stream>>>(x, wcrz, wry, scale, st);
    k3_measure<<<512, 256, 0, stream>>>(wry, st, accum, done, out);
}

// Round 5
// 59.907 us; speedup vs baseline: 4.3517x; 2.4581x over previous
//
#include <hip/hip_runtime.h>

#define PI_F 3.14159265358979323846f
#define INV_SQRT2 0.70710678118654752440f

// Light-cone exact reduction: z(n,q) depends only on qubits (q-3..q+3) mod 16.
// Per (n,q): 7-qubit (128-amp) sim with the surviving gates:
//   product init -> 6x CRZ(i,i+1) [D0 window] -> RY(alpha) on {q-2,q,q+2}
//   -> 2x CRZ {(q-2,q),(q,q+2)} [D1 window] -> RY(beta_q) on q -> <Z_q>.
// One wave per (n,q): 64 lanes x 2 amps (local qubit 6 = register bit).
__global__ __launch_bounds__(256)
void lightcone_qsim(const float* __restrict__ x, const float* __restrict__ wcrz,
                    const float* __restrict__ wry, const float* __restrict__ scale_p,
                    float* __restrict__ out) {
    const int tid = threadIdx.x, wid = tid >> 6, l = tid & 63;
    const int n = blockIdx.x >> 2;                 // circuit 0..63
    const int q = ((blockIdx.x & 3) << 2) | wid;   // measured qubit 0..15

    __shared__ float v0[16], v1[16];       // init state per qubit: RY(enc)*H|0>
    __shared__ float ac[16], as_[16];      // alpha = wry0 + enc (half-angle c/s)
    __shared__ float bcx[16], bsx[16];     // beta = wry1
    __shared__ float t0[16], t1[16];       // CRZ half-angles, layers 0/1

    if (tid < 16) {
        const int qq = tid, b = n >> 3, p = n & 7, h = qq >> 2, w = qq & 3;
        const float enc = tanhf(x[b*128 + h*32 + p*4 + w] * scale_p[0]) * PI_F;
        float s, c; sincosf(0.5f * enc, &s, &c);
        v0[qq] = (c - s) * INV_SQRT2;
        v1[qq] = (c + s) * INV_SQRT2;
        sincosf(0.5f * (wry[qq] + enc), &as_[qq], &ac[qq]);   // merged RY(w0)+RY(enc)
        sincosf(0.5f * wry[16 + qq], &bsx[qq], &bcx[qq]);
        t0[qq] = 0.5f * wcrz[qq];
        t1[qq] = 0.5f * wcrz[16 + qq];
    }
    __syncthreads();

    // window qubits: local i -> global m[i] = q-3+i (mod 16); center = local 3
    int m[7];
#pragma unroll
    for (int i = 0; i < 7; ++i) m[i] = (q + 13 + i) & 15;

    int bit[6];
#pragma unroll
    for (int i = 0; i < 6; ++i) bit[i] = (l >> i) & 1;

    // product init (real); two amps per lane: local bit 6 = r in {0,1}
    float prod = 1.f;
#pragma unroll
    for (int i = 0; i < 6; ++i) prod *= bit[i] ? v1[m[i]] : v0[m[i]];
    const float prod0 = prod * v0[m[6]];
    const float prod1 = prod * v1[m[6]];

    // D0 window: CRZ(local i -> i+1), i=0..5. phase = b_i ? (b_{i+1} ? +t : -t) : 0
    float base = 0.f;
#pragma unroll
    for (int i = 0; i < 5; ++i)
        if (bit[i]) base += bit[i + 1] ? t0[m[i]] : -t0[m[i]];
    const float ang0 = base + (bit[5] ? -t0[m[5]] : 0.f);   // r=0 (b6=0)
    const float ang1 = base + (bit[5] ? +t0[m[5]] : 0.f);   // r=1 (b6=1)
    float s0, c0, s1, c1;
    sincosf(ang0, &s0, &c0);
    sincosf(ang1, &s1, &c1);
    float2 a0 = make_float2(prod0 * c0, prod0 * s0);
    float2 a1 = make_float2(prod1 * c1, prod1 * s1);

    // RY(alpha) on local qubits 1,3,5 (= global q-2, q, q+2): lane-shuffle butterflies
#pragma unroll
    for (int t = 0; t < 3; ++t) {
        const int i = 1 + 2 * t, mask = 1 << i;
        const float c = ac[m[i]], s = as_[m[i]];
        const float sg = bit[i] ? s : -s;
        const float p0x = __shfl_xor(a0.x, mask, 64), p0y = __shfl_xor(a0.y, mask, 64);
        const float p1x = __shfl_xor(a1.x, mask, 64), p1y = __shfl_xor(a1.y, mask, 64);
        a0 = make_float2(c*a0.x + sg*p0x, c*a0.y + sg*p0y);
        a1 = make_float2(c*a1.x + sg*p1x, c*a1.y + sg*p1y);
    }

    // D1 window: CRZ(local 1 -> 3) and CRZ(local 3 -> 5); lane bits only
    float phi1 = 0.f;
    if (bit[1]) phi1 += bit[3] ? t1[m[1]] : -t1[m[1]];
    if (bit[3]) phi1 += bit[5] ? t1[m[3]] : -t1[m[3]];
    float sp, cp; sincosf(phi1, &sp, &cp);
    a0 = make_float2(a0.x*cp - a0.y*sp, a0.x*sp + a0.y*cp);
    a1 = make_float2(a1.x*cp - a1.y*sp, a1.x*sp + a1.y*cp);

    // RY(beta_q) on local 3
    {
        const int mask = 8;
        const float c = bcx[q], s = bsx[q];
        const float sg = bit[3] ? s : -s;
        const float p0x = __shfl_xor(a0.x, mask, 64), p0y = __shfl_xor(a0.y, mask, 64);
        const float p1x = __shfl_xor(a1.x, mask, 64), p1y = __shfl_xor(a1.y, mask, 64);
        a0 = make_float2(c*a0.x + sg*p0x, c*a0.y + sg*p0y);
        a1 = make_float2(c*a1.x + sg*p1x, c*a1.y + sg*p1y);
    }

    // <Z_center>: sum (1-2*b3) * |amp|^2 over all 128 amps
    float val = a0.x*a0.x + a0.y*a0.y + a1.x*a1.x + a1.y*a1.y;
    val = bit[3] ? -val : val;
#pragma unroll
    for (int off = 1; off < 64; off <<= 1) val += __shfl_xor(val, off, 64);

    if (l == 0) {
        const int b = n >> 3, p = n & 7, h = q >> 2, w = q & 3;
        out[b*128 + h*32 + p*4 + w] = fminf(1.f, fmaxf(-1.f, val));
    }
}

extern "C" void kernel_launch(void* const* d_in, const int* in_sizes, int n_in,
                              void* d_out, int out_size, void* d_ws, size_t ws_size,
                              hipStream_t stream) {
    const float* x     = (const float*)d_in[0];
    const float* wcrz  = (const float*)d_in[1];
    const float* wry   = (const float*)d_in[2];
    const float* scale = (const float*)d_in[3];
    float* out = (float*)d_out;

    lightcone_qsim<<<256, 256, 0, stream>>>(x, wcrz, wry, scale, out);
}